// Round 12
// baseline (348.178 us; speedup 1.0000x reference)
//
#include <hip/hip_runtime.h>
#include <hip/hip_bf16.h>
#include <math.h>

#define N_USERS_C 100000
#define BK_SHIFT 9
#define BK_NODES 512
#define NBK_PAD 304   // >= nbk(293), breaks pow2 strides

typedef __bf16 bf8_t __attribute__((ext_vector_type(8)));
typedef float f32x4 __attribute__((ext_vector_type(4)));

__device__ __forceinline__ unsigned int pack_bf16(float a, float b) {
    __hip_bfloat16 ha = __float2bfloat16(a), hb = __float2bfloat16(b);
    return ((unsigned int)(*(unsigned short*)&hb) << 16) | (unsigned int)(*(unsigned short*)&ha);
}
__device__ __forceinline__ unsigned short bf16_1(float a) {
    __hip_bfloat16 ha = __float2bfloat16(a);
    return *(unsigned short*)&ha;
}
__device__ __forceinline__ float bf_lo(unsigned int u) { return __uint_as_float(u << 16); }
__device__ __forceinline__ float bf_hi(unsigned int u) { return __uint_as_float(u & 0xffff0000u); }

// ---------------- merged: bucket histogram (wave-replicated) || x->bf16 ----------------
__global__ __launch_bounds__(512) void k_pre(const int* __restrict__ dst, int* __restrict__ chist,
                                             const float* __restrict__ x, unsigned int* __restrict__ xb,
                                             int E, int nbk, int EB2, int n2) {
    __shared__ int lcntW[8][NBK_PAD];
    const int bid = blockIdx.x;
    const int t = threadIdx.x;
    const int w = t >> 6;
    if (bid < EB2) {
        for (int i = t; i < 8 * NBK_PAD; i += 512) ((int*)lcntW)[i] = 0;
        __syncthreads();
        int e0 = bid * 4096;
        #pragma unroll
        for (int j = 0; j < 8; ++j) {
            int e = e0 + j * 512 + t;
            if (e < E) atomicAdd(&lcntW[w][dst[e] >> BK_SHIFT], 1);
        }
        __syncthreads();
        if (t < nbk) {
            int s = 0;
            #pragma unroll
            for (int i = 0; i < 8; ++i) s += lcntW[i][t];
            if (s) atomicAdd(&chist[t], s);
        }
    } else {
        int base = (bid - EB2) * 2048;
        #pragma unroll
        for (int j = 0; j < 4; ++j) {
            int i = base + j * 512 + t;
            if (i < n2) {
                float2 v = ((const float2*)x)[i];
                xb[i] = pack_bf16(v.x, v.y);
            }
        }
    }
}

// ---------------- pass 1: counting sort, wave-replicated counters ----------------
__global__ __launch_bounds__(512) void k_bin(const int* __restrict__ src,
                                             const int* __restrict__ dst,
                                             const int* __restrict__ chist,
                                             int* __restrict__ bcursor0,
                                             int* __restrict__ pairBuf, int E, int nbk) {
    __shared__ int lcntW[8][NBK_PAD];   // counts -> per-wave placement cursors
    __shared__ int delta[NBK_PAD];
    __shared__ int waveSum[8];
    __shared__ int cWaveSum[8];
    __shared__ int sPack[4096];
    __shared__ unsigned short sBkt[4096];
    const int t = threadIdx.x;
    const int lane = t & 63;
    const int w = t >> 6;
    const int e0 = blockIdx.x * 4096;
    for (int i = t; i < 8 * NBK_PAD; i += 512) ((int*)lcntW)[i] = 0;
    __syncthreads();

    int mySrc[8], myB[8], myDl[8];
    #pragma unroll
    for (int j = 0; j < 8; ++j) {
        int e = e0 + j * 512 + t;
        if (e < E) {
            int sv = src[e], dv = dst[e];
            mySrc[j] = sv; myB[j] = dv >> BK_SHIFT; myDl[j] = dv & (BK_NODES - 1);
            atomicAdd(&lcntW[w][myB[j]], 1);
        } else myB[j] = -1;
    }
    __syncthreads();

    // thread t owns bucket t: fold 8 wave counts -> per-wave bases + total
    int baseW[8];
    int v = 0;
    if (t < nbk) {
        #pragma unroll
        for (int i = 0; i < 8; ++i) { baseW[i] = v; v += lcntW[i][t]; }
    }
    // block-local exclusive scan of totals (wave shuffle)
    int inc = v;
    #pragma unroll
    for (int off = 1; off < 64; off <<= 1) {
        int n = __shfl_up(inc, off);
        if (lane >= off) inc += n;
    }
    if (lane == 63) waveSum[w] = inc;
    // local exclusive scan of chist for global bucket bases
    int cv = (t < nbk) ? chist[t] : 0;
    int cinc = cv;
    #pragma unroll
    for (int off = 1; off < 64; off <<= 1) {
        int n = __shfl_up(cinc, off);
        if (lane >= off) cinc += n;
    }
    if (lane == 63) cWaveSum[w] = cinc;
    __syncthreads();
    int wp = 0, cwp = 0;
    #pragma unroll
    for (int i = 0; i < 8; ++i) {
        wp += (i < w) ? waveSum[i] : 0;
        cwp += (i < w) ? cWaveSum[i] : 0;
    }
    int ex = wp + inc - v;         // block-local exclusive prefix
    int cbase = cwp + cinc - cv;   // global bucket base
    if (t < nbk) {
        int gb = cbase + ((v > 0) ? atomicAdd(&bcursor0[t], v) : 0);
        delta[t] = gb - ex;
        #pragma unroll
        for (int i = 0; i < 8; ++i) lcntW[i][t] = ex + baseW[i];   // per-wave cursors
    }
    __syncthreads();

    #pragma unroll
    for (int j = 0; j < 8; ++j) {
        if (myB[j] >= 0) {
            int p = atomicAdd(&lcntW[w][myB[j]], 1);
            sPack[p] = mySrc[j] | (myDl[j] << 18);   // src < 2^18
            sBkt[p] = (unsigned short)myB[j];
        }
    }
    __syncthreads();
    int total = (E - e0 < 4096) ? (E - e0) : 4096;
    for (int i = t; i < total; i += 512)
        pairBuf[delta[sBkt[i]] + i] = sPack[i];
}

// ---------------- pass 2: per-bucket rowstart/dinv + csr scatter (wave-replicated) ----------------
__global__ __launch_bounds__(512) void k_bscatter(const int* __restrict__ pairBuf,
                                                  const int* __restrict__ chist,
                                                  int* __restrict__ rowstart,
                                                  float* __restrict__ dinv,
                                                  int* __restrict__ csr, int N, int E, int nbk) {
    const int b = blockIdx.x;
    const int n0 = b << BK_SHIFT;
    int nn = N - n0; if (nn > BK_NODES) nn = BK_NODES;
    __shared__ int histW[8][BK_NODES + 8];   // counts -> per-wave cursors
    __shared__ int waveSum[8];
    __shared__ int sE0, sE1;
    const int t = threadIdx.x;
    const int lane = t & 63;
    const int w = t >> 6;

    // local exclusive scan of chist -> this bucket's [e0,e1)
    {
        int cv = (t < nbk) ? chist[t] : 0;
        int cinc = cv;
        #pragma unroll
        for (int off = 1; off < 64; off <<= 1) {
            int n = __shfl_up(cinc, off);
            if (lane >= off) cinc += n;
        }
        if (lane == 63) waveSum[w] = cinc;
        __syncthreads();
        int cwp = 0;
        #pragma unroll
        for (int i = 0; i < 8; ++i) cwp += (i < w) ? waveSum[i] : 0;
        if (t == b) { sE0 = cwp + cinc - cv; sE1 = cwp + cinc; }
    }
    for (int i = t; i < 8 * (BK_NODES + 8); i += 512) ((int*)histW)[i] = 0;
    __syncthreads();
    const int e0 = sE0, e1 = sE1;

    for (int e = e0 + t; e < e1; e += 512)
        atomicAdd(&histW[w][pairBuf[e] >> 18], 1);
    __syncthreads();

    int baseW[8];
    int v = 0;
    if (t < nn) {
        #pragma unroll
        for (int i = 0; i < 8; ++i) { baseW[i] = v; v += histW[i][t]; }
    }
    int inc = v;
    #pragma unroll
    for (int off = 1; off < 64; off <<= 1) {
        int n = __shfl_up(inc, off);
        if (lane >= off) inc += n;
    }
    if (lane == 63) waveSum[w] = inc;
    __syncthreads();
    int wp = 0;
    #pragma unroll
    for (int i = 0; i < 8; ++i) wp += (i < w) ? waveSum[i] : 0;
    int ex = wp + inc - v;
    if (t < nn) {
        int r = e0 + ex;
        rowstart[n0 + t] = r;
        dinv[n0 + t] = rsqrtf((float)(v + 1));
        #pragma unroll
        for (int i = 0; i < 8; ++i) histW[i][t] = r + baseW[i];   // per-wave global cursors
    }
    if (b == gridDim.x - 1 && t == 0) rowstart[N] = E;
    __syncthreads();
    for (int e = e0 + t; e < e1; e += 512) {
        int pk = pairBuf[e];
        int pos = atomicAdd(&histW[w][pk >> 18], 1);
        csr[pos] = pk & 0x3FFFF;
    }
}

// ---------------- gather1: aggXb = bf16(A_hat x); all-bf16, dwordx4, 8 edges/instr ----------------
__global__ __launch_bounds__(256) void k_gather1(const int* __restrict__ rowstart,
                                                 const int* __restrict__ csr,
                                                 const float* __restrict__ dinv,
                                                 const uint4* __restrict__ xb4,
                                                 unsigned int* __restrict__ outb, int N) {
    const int node = blockIdx.x * 4 + (threadIdx.x >> 6);
    const int l = threadIdx.x & 63;
    if (node >= N) return;
    const int sub = l >> 3;
    const int c = l & 7;
    const int rs = rowstart[node];
    const int re = rowstart[node + 1];

    float acc[8] = {0.f, 0.f, 0.f, 0.f, 0.f, 0.f, 0.f, 0.f};
    for (int base = rs; base < re; base += 64) {
        int idx = base + l;
        int sE = (idx < re) ? csr[idx] : 0;
        float dE = (idx < re) ? dinv[sE] : 0.0f;
        int cnt = re - base; if (cnt > 64) cnt = 64;
        int groups = (cnt + 7) >> 3;
        for (int g = 0; g < groups; ++g) {
            int e = g * 8 + sub;
            int sk = __shfl(sE, e);
            float dk = __shfl(dE, e);
            uint4 u = xb4[(size_t)sk * 8 + c];
            acc[0] += dk * bf_lo(u.x); acc[1] += dk * bf_hi(u.x);
            acc[2] += dk * bf_lo(u.y); acc[3] += dk * bf_hi(u.y);
            acc[4] += dk * bf_lo(u.z); acc[5] += dk * bf_hi(u.z);
            acc[6] += dk * bf_lo(u.w); acc[7] += dk * bf_hi(u.w);
        }
    }
    #pragma unroll
    for (int m = 8; m < 64; m <<= 1)
        #pragma unroll
        for (int i = 0; i < 8; ++i) acc[i] += __shfl_xor(acc[i], m);
    if (sub == 0) {
        float dd = dinv[node];
        float d2 = dd * dd;
        uint4 us = xb4[(size_t)node * 8 + c];   // bf16 self term
        uint4 o;
        o.x = pack_bf16(dd * acc[0] + d2 * bf_lo(us.x), dd * acc[1] + d2 * bf_hi(us.x));
        o.y = pack_bf16(dd * acc[2] + d2 * bf_lo(us.y), dd * acc[3] + d2 * bf_hi(us.y));
        o.z = pack_bf16(dd * acc[4] + d2 * bf_lo(us.z), dd * acc[5] + d2 * bf_hi(us.z));
        o.w = pack_bf16(dd * acc[6] + d2 * bf_lo(us.w), dd * acc[7] + d2 * bf_hi(us.w));
        ((uint4*)outb)[(size_t)node * 8 + c] = o;
    }
}

// ---------------- fused layer1+layer2 via MFMA bf16 ----------------
__global__ __launch_bounds__(256) void k_layer12(const unsigned int* __restrict__ aggXb,
                                                 const float* __restrict__ W1,
                                                 const float* __restrict__ b1,
                                                 const float* __restrict__ W2,
                                                 const float* __restrict__ dinv,
                                                 unsigned int* __restrict__ xs2b, int N) {
    __shared__ unsigned int sA[64 * 36];    // aggX bf16; later C2 out-stage
    __shared__ unsigned int sB[128 * 36];   // W1T bf16 (stride 36); later W2T (stride 68)
    __shared__ unsigned int sC[64 * 68];    // h1 bf16 (stride 68 uints = 136 bf16)
    const int t = threadIdx.x;
    const int w = t >> 6;
    const int l = t & 63;
    const int n16 = l & 15;
    const int quad = l >> 4;
    const int row0 = blockIdx.x * 64;

    for (int i = t; i < 512; i += 256) {
        int r = i >> 3, c = i & 7;
        int row = row0 + r;
        uint4 u = (row < N) ? ((const uint4*)aggXb)[(size_t)row * 8 + c]
                            : make_uint4(0u, 0u, 0u, 0u);
        *(uint4*)&sA[r * 36 + c * 4] = u;
    }
    for (int i = t; i < 4096; i += 256) {
        int kp = i >> 7, n = i & 127;
        float a0 = W1[(size_t)(2 * kp) * 128 + n];
        float a1 = W1[(size_t)(2 * kp + 1) * 128 + n];
        sB[n * 36 + kp] = pack_bf16(a0, a1);
    }
    __syncthreads();

    f32x4 acc[8];
    #pragma unroll
    for (int nt = 0; nt < 8; ++nt) acc[nt] = (f32x4){0.f, 0.f, 0.f, 0.f};
    {
        const int am = w * 16 + n16;
        bf8_t a0 = *(const bf8_t*)&sA[am * 36 + quad * 4];
        bf8_t a1 = *(const bf8_t*)&sA[am * 36 + 16 + quad * 4];
        #pragma unroll
        for (int nt = 0; nt < 8; ++nt) {
            bf8_t b0 = *(const bf8_t*)&sB[(nt * 16 + n16) * 36 + quad * 4];
            bf8_t b1v = *(const bf8_t*)&sB[(nt * 16 + n16) * 36 + 16 + quad * 4];
            acc[nt] = __builtin_amdgcn_mfma_f32_16x16x32_bf16(a0, b0, acc[nt], 0, 0, 0);
            acc[nt] = __builtin_amdgcn_mfma_f32_16x16x32_bf16(a1, b1v, acc[nt], 0, 0, 0);
        }
    }
    __syncthreads();

    {
        unsigned short* sC16 = (unsigned short*)sC;
        #pragma unroll
        for (int nt = 0; nt < 8; ++nt) {
            int col = nt * 16 + n16;
            float bv = b1[col];
            #pragma unroll
            for (int reg = 0; reg < 4; ++reg) {
                int r = w * 16 + quad * 4 + reg;
                sC16[r * 136 + col] = bf16_1(fmaxf(acc[nt][reg] + bv, 0.f));
            }
        }
    }
    for (int i = t; i < 4096; i += 256) {
        int kp = i >> 6, n = i & 63;
        float a0 = W2[(size_t)(2 * kp) * 64 + n];
        float a1 = W2[(size_t)(2 * kp + 1) * 64 + n];
        sB[n * 68 + kp] = pack_bf16(a0, a1);
    }
    __syncthreads();

    f32x4 acc2[4];
    #pragma unroll
    for (int nt = 0; nt < 4; ++nt) acc2[nt] = (f32x4){0.f, 0.f, 0.f, 0.f};
    {
        const int am = w * 16 + n16;
        #pragma unroll
        for (int ks = 0; ks < 4; ++ks) {
            bf8_t a = *(const bf8_t*)&sC[am * 68 + ks * 16 + quad * 4];
            #pragma unroll
            for (int nt = 0; nt < 4; ++nt) {
                bf8_t b = *(const bf8_t*)&sB[(nt * 16 + n16) * 68 + ks * 16 + quad * 4];
                acc2[nt] = __builtin_amdgcn_mfma_f32_16x16x32_bf16(a, b, acc2[nt], 0, 0, 0);
            }
        }
    }

    {
        unsigned short* sA16 = (unsigned short*)sA;
        #pragma unroll
        for (int reg = 0; reg < 4; ++reg) {
            int r = w * 16 + quad * 4 + reg;
            int row = row0 + r;
            float dd = (row < N) ? dinv[row] : 0.f;
            #pragma unroll
            for (int nt = 0; nt < 4; ++nt)
                sA16[r * 72 + nt * 16 + n16] = bf16_1(acc2[nt][reg] * dd);
        }
    }
    __syncthreads();
    for (int i = t; i < 512; i += 256) {
        int r = i >> 3, c = i & 7;
        int row = row0 + r;
        if (row < N)
            ((uint4*)xs2b)[(size_t)row * 8 + c] = *(uint4*)&sA[r * 36 + c * 4];
    }
}

// ---------------- gather_pairs (dwordx4 loads): cB[b] = [h2(u), h2(i)] ----------------
__global__ __launch_bounds__(256) void k_gather_pairs(const int* __restrict__ rowstart,
                                                      const int* __restrict__ csr,
                                                      const float* __restrict__ dinv,
                                                      const uint4* __restrict__ xs2b4,
                                                      const float* __restrict__ b2,
                                                      const int* __restrict__ ui,
                                                      const int* __restrict__ ii,
                                                      float* __restrict__ cB, int B) {
    const int wave = threadIdx.x >> 6;
    const int b = blockIdx.x * 2 + (wave >> 1);
    const int half = wave & 1;
    const int l = threadIdx.x & 63;
    const int sub = l >> 3;
    const int c = l & 7;
    if (b >= B) return;
    const int node = (half == 0) ? (ui[b] - 1) : (N_USERS_C + ii[b] - 1);
    const int rs = rowstart[node];
    const int re = rowstart[node + 1];

    float acc[8] = {0.f, 0.f, 0.f, 0.f, 0.f, 0.f, 0.f, 0.f};
    for (int base = rs; base < re; base += 64) {
        int idx = base + l;
        int sE = (idx < re) ? csr[idx] : 0;
        float vE = (idx < re) ? 1.0f : 0.0f;
        int cnt = re - base; if (cnt > 64) cnt = 64;
        int groups = (cnt + 7) >> 3;
        for (int g = 0; g < groups; ++g) {
            int e = g * 8 + sub;
            int sk = __shfl(sE, e);
            float vk = __shfl(vE, e);
            uint4 u = xs2b4[(size_t)sk * 8 + c];
            acc[0] += vk * bf_lo(u.x); acc[1] += vk * bf_hi(u.x);
            acc[2] += vk * bf_lo(u.y); acc[3] += vk * bf_hi(u.y);
            acc[4] += vk * bf_lo(u.z); acc[5] += vk * bf_hi(u.z);
            acc[6] += vk * bf_lo(u.w); acc[7] += vk * bf_hi(u.w);
        }
    }
    #pragma unroll
    for (int m = 8; m < 64; m <<= 1)
        #pragma unroll
        for (int i = 0; i < 8; ++i) acc[i] += __shfl_xor(acc[i], m);
    if (sub == 0) {
        float dd = dinv[node];
        uint4 us = xs2b4[(size_t)node * 8 + c];
        float4 s0, s1;
        s0.x = bf_lo(us.x); s0.y = bf_hi(us.x); s0.z = bf_lo(us.y); s0.w = bf_hi(us.y);
        s1.x = bf_lo(us.z); s1.y = bf_hi(us.z); s1.z = bf_lo(us.w); s1.w = bf_hi(us.w);
        float4 bb0 = ((const float4*)b2)[c * 2];
        float4 bb1 = ((const float4*)b2)[c * 2 + 1];
        float4 o0, o1;
        o0.x = dd * (acc[0] + s0.x) + bb0.x;
        o0.y = dd * (acc[1] + s0.y) + bb0.y;
        o0.z = dd * (acc[2] + s0.z) + bb0.z;
        o0.w = dd * (acc[3] + s0.w) + bb0.w;
        o1.x = dd * (acc[4] + s1.x) + bb1.x;
        o1.y = dd * (acc[5] + s1.y) + bb1.y;
        o1.z = dd * (acc[6] + s1.z) + bb1.z;
        o1.w = dd * (acc[7] + s1.w) + bb1.w;
        ((float4*)cB)[(size_t)b * 32 + half * 16 + c * 2] = o0;
        ((float4*)cB)[(size_t)b * 32 + half * 16 + c * 2 + 1] = o1;
    }
}

// ---------------- fused MLP: 32 rows/block ----------------
__global__ __launch_bounds__(256) void k_mlp(const float* __restrict__ cB,
                                             const float* __restrict__ fcW1, const float* __restrict__ fcb1,
                                             const float* __restrict__ g1,   const float* __restrict__ be1,
                                             const float* __restrict__ fcW2, const float* __restrict__ fcb2,
                                             const float* __restrict__ g2,   const float* __restrict__ be2,
                                             const float* __restrict__ fcW3, const float* __restrict__ fcb3,
                                             float* __restrict__ out) {
    __shared__ float sIn[32 * 128];
    __shared__ float sW[64 * 128];
    const int t = threadIdx.x;
    const int row0 = blockIdx.x * 32;
    const int rg = t >> 4;
    const int cg = t & 15;

    for (int i = t; i < 1024; i += 256) {
        int r = i >> 5, c4 = i & 31;
        *(float4*)&sIn[r * 128 + c4 * 4] = *(const float4*)&cB[(size_t)(row0 + r) * 128 + c4 * 4];
    }

    float acc1[2][8];
    {
        float4 b01 = *(const float4*)&fcb1[cg * 8];
        float4 b23 = *(const float4*)&fcb1[cg * 8 + 4];
        #pragma unroll
        for (int jj = 0; jj < 2; ++jj) {
            acc1[jj][0] = b01.x; acc1[jj][1] = b01.y; acc1[jj][2] = b01.z; acc1[jj][3] = b01.w;
            acc1[jj][4] = b23.x; acc1[jj][5] = b23.y; acc1[jj][6] = b23.z; acc1[jj][7] = b23.w;
        }
    }
    for (int s = 0; s < 2; ++s) {
        __syncthreads();
        for (int i = t; i < 2048; i += 256) {
            int k = i >> 5, c4 = i & 31;
            *(float4*)&sW[k * 128 + c4 * 4] = *(const float4*)&fcW1[(size_t)(64 * s + k) * 128 + c4 * 4];
        }
        __syncthreads();
        for (int k0 = 0; k0 < 64; k0 += 4) {
            float4 a[2];
            #pragma unroll
            for (int jj = 0; jj < 2; ++jj)
                a[jj] = *(const float4*)&sIn[(rg * 2 + jj) * 128 + 64 * s + k0];
            #pragma unroll
            for (int kk = 0; kk < 4; ++kk) {
                float4 w0 = *(const float4*)&sW[(k0 + kk) * 128 + cg * 8];
                float4 w1 = *(const float4*)&sW[(k0 + kk) * 128 + cg * 8 + 4];
                #pragma unroll
                for (int jj = 0; jj < 2; ++jj) {
                    float f = ((const float*)&a[jj])[kk];
                    acc1[jj][0] += f * w0.x; acc1[jj][1] += f * w0.y;
                    acc1[jj][2] += f * w0.z; acc1[jj][3] += f * w0.w;
                    acc1[jj][4] += f * w1.x; acc1[jj][5] += f * w1.y;
                    acc1[jj][6] += f * w1.z; acc1[jj][7] += f * w1.w;
                }
            }
        }
    }
    __syncthreads();

    {
        float4 g01 = *(const float4*)&g1[cg * 8];
        float4 g23 = *(const float4*)&g1[cg * 8 + 4];
        float4 e01 = *(const float4*)&be1[cg * 8];
        float4 e23 = *(const float4*)&be1[cg * 8 + 4];
        float gv[8] = {g01.x, g01.y, g01.z, g01.w, g23.x, g23.y, g23.z, g23.w};
        float ev[8] = {e01.x, e01.y, e01.z, e01.w, e23.x, e23.y, e23.z, e23.w};
        #pragma unroll
        for (int jj = 0; jj < 2; ++jj) {
            float s_ = 0.f, ss = 0.f;
            #pragma unroll
            for (int c = 0; c < 8; ++c) { float v = acc1[jj][c]; s_ += v; ss += v * v; }
            #pragma unroll
            for (int m = 1; m < 16; m <<= 1) { s_ += __shfl_xor(s_, m); ss += __shfl_xor(ss, m); }
            float mu = s_ * (1.0f / 128.0f);
            float var = ss * (1.0f / 128.0f) - mu * mu;
            float rs = rsqrtf(var + 1e-5f);
            #pragma unroll
            for (int c = 0; c < 8; ++c) {
                float z = (acc1[jj][c] - mu) * rs * gv[c] + ev[c];
                sIn[(rg * 2 + jj) * 128 + cg * 8 + c] = fmaxf(z, 0.f);
            }
        }
    }
    __syncthreads();

    for (int i = t; i < 2048; i += 256) {
        int k = i >> 4, c4 = i & 15;
        *(float4*)&sW[k * 64 + c4 * 4] = *(const float4*)&fcW2[(size_t)k * 64 + c4 * 4];
    }
    float acc2[2][4];
    {
        float4 bv = *(const float4*)&fcb2[cg * 4];
        #pragma unroll
        for (int jj = 0; jj < 2; ++jj) {
            acc2[jj][0] = bv.x; acc2[jj][1] = bv.y; acc2[jj][2] = bv.z; acc2[jj][3] = bv.w;
        }
    }
    __syncthreads();
    for (int k0 = 0; k0 < 128; k0 += 4) {
        float4 a[2], w[4];
        #pragma unroll
        for (int jj = 0; jj < 2; ++jj) a[jj] = *(const float4*)&sIn[(rg * 2 + jj) * 128 + k0];
        #pragma unroll
        for (int kk = 0; kk < 4; ++kk) w[kk] = *(const float4*)&sW[(k0 + kk) * 64 + cg * 4];
        #pragma unroll
        for (int jj = 0; jj < 2; ++jj) {
            const float* aj = (const float*)&a[jj];
            #pragma unroll
            for (int kk = 0; kk < 4; ++kk) {
                float f = aj[kk];
                acc2[jj][0] += f * w[kk].x; acc2[jj][1] += f * w[kk].y;
                acc2[jj][2] += f * w[kk].z; acc2[jj][3] += f * w[kk].w;
            }
        }
    }

    {
        float4 gv4 = *(const float4*)&g2[cg * 4];
        float4 ev4 = *(const float4*)&be2[cg * 4];
        float4 w34 = *(const float4*)&fcW3[cg * 4];
        float gv[4] = {gv4.x, gv4.y, gv4.z, gv4.w};
        float ev[4] = {ev4.x, ev4.y, ev4.z, ev4.w};
        float wv[4] = {w34.x, w34.y, w34.z, w34.w};
        float b3 = fcb3[0];
        #pragma unroll
        for (int jj = 0; jj < 2; ++jj) {
            float s_ = 0.f, ss = 0.f;
            #pragma unroll
            for (int c = 0; c < 4; ++c) { float v = acc2[jj][c]; s_ += v; ss += v * v; }
            #pragma unroll
            for (int m = 1; m < 16; m <<= 1) { s_ += __shfl_xor(s_, m); ss += __shfl_xor(ss, m); }
            float mu = s_ * (1.0f / 64.0f);
            float var = ss * (1.0f / 64.0f) - mu * mu;
            float rs = rsqrtf(var + 1e-5f);
            float p = 0.f;
            #pragma unroll
            for (int c = 0; c < 4; ++c) {
                float z = fmaxf((acc2[jj][c] - mu) * rs * gv[c] + ev[c], 0.f);
                p += z * wv[c];
            }
            #pragma unroll
            for (int m = 1; m < 16; m <<= 1) p += __shfl_xor(p, m);
            if (cg == 0) out[row0 + rg * 2 + jj] = 1.0f / (1.0f + expf(-(p + b3)));
        }
    }
}

extern "C" void kernel_launch(void* const* d_in, const int* in_sizes, int n_in,
                              void* d_out, int out_size, void* d_ws, size_t ws_size,
                              hipStream_t stream) {
    const float* x    = (const float*)d_in[0];
    const int*   src  = (const int*)d_in[1];
    const int*   dst  = (const int*)d_in[2];
    const int*   ui   = (const int*)d_in[3];
    const int*   ii   = (const int*)d_in[4];
    const float* W1   = (const float*)d_in[5];
    const float* b1   = (const float*)d_in[6];
    const float* W2   = (const float*)d_in[7];
    const float* b2   = (const float*)d_in[8];
    const float* fcW1 = (const float*)d_in[9];
    const float* fcb1 = (const float*)d_in[10];
    const float* g1   = (const float*)d_in[11];
    const float* be1  = (const float*)d_in[12];
    const float* fcW2 = (const float*)d_in[13];
    const float* fcb2 = (const float*)d_in[14];
    const float* g2   = (const float*)d_in[15];
    const float* be2  = (const float*)d_in[16];
    const float* fcW3 = (const float*)d_in[17];
    const float* fcb3 = (const float*)d_in[18];
    float* out = (float*)d_out;

    const int N = in_sizes[0] / 64;          // 150000
    const int E = in_sizes[1];               // 2400000
    const int B = in_sizes[3];               // 16384
    const int NBK = (N + BK_NODES - 1) >> BK_SHIFT;   // 293
    const int EB2 = (E + 4095) / 4096;       // 586 (hist + bin blocks)
    const int n2 = N * 32;
    const int XB = (n2 + 2047) / 2048;

    // ---- workspace layout (~77 MB) ----
    float* ws   = (float*)d_ws;
    float* dinv = ws;                                   // N
    int* rowstart = (int*)(dinv + N);                   // N+1
    int* csr      = rowstart + (N + 1);                 // E
    unsigned int* xb = (unsigned int*)(csr + E);        // N*32 (bf16 x)
    unsigned int* bufU = xb + (size_t)N * 32;           // N*32: CSR scratch, then aggXb
    unsigned int* xs2b = bufU + (size_t)N * 32;         // N*32 (bf16 xs2)
    float* cB = (float*)(xs2b + (size_t)N * 32);        // B*128 f32
    int* pairBuf = (int*)bufU;                          // E
    int* chist   = pairBuf + E;                         // 512
    int* bcursor = chist + 512;                         // 512 (adjacent: one memset)
    unsigned int* aggXb = bufU;                         // N*32 (bf16 aggX)

    // ---- CSR build + bf16 conversion ----
    hipMemsetAsync(chist, 0, 1024 * sizeof(int), stream);   // chist + bcursor
    k_pre<<<EB2 + XB, 512, 0, stream>>>(dst, chist, x, xb, E, NBK, EB2, n2);
    k_bin<<<EB2, 512, 0, stream>>>(src, dst, chist, bcursor, pairBuf, E, NBK);
    k_bscatter<<<NBK, 512, 0, stream>>>(pairBuf, chist, rowstart, dinv, csr, N, E, NBK);

    // ---- layer 1 gather ----
    k_gather1<<<(N + 3) / 4, 256, 0, stream>>>(rowstart, csr, dinv, (const uint4*)xb, aggXb, N);

    // ---- fused layer1+layer2 GEMMs (MFMA bf16) ----
    k_layer12<<<(N + 63) / 64, 256, 0, stream>>>(aggXb, W1, b1, W2, dinv, xs2b, N);

    // ---- pruned gather2 + concat ----
    k_gather_pairs<<<(B + 1) / 2, 256, 0, stream>>>(rowstart, csr, dinv, (const uint4*)xs2b,
                                                    b2, ui, ii, cB, B);

    // ---- fused MLP ----
    k_mlp<<<B / 32, 256, 0, stream>>>(cB, fcW1, fcb1, g1, be1,
                                      fcW2, fcb2, g2, be2, fcW3, fcb3, out);
}